// Round 13
// baseline (161.173 us; speedup 1.0000x reference)
//
#include <hip/hip_runtime.h>
#include <math.h>

// Problem constants (fixed by the reference).
#define kB 2
#define kS 2048
#define kD 1024
#define kH 16
#define kDk 64
#define kM (kB * kS)  // 4096 rows of x
#define kNT (kD / 64) // 16 K-tiles of BK=64
// log2(10000)
#define kLog2Theta 13.287712379549449
// 0.125 (1/sqrt(dk)) * log2(e): folded into stored Q; softmax in exp2 space
#define C_SCALE 0.18033688011112042f

typedef __attribute__((ext_vector_type(4))) float f32x4;
typedef __attribute__((ext_vector_type(16))) float f32x16;
typedef __attribute__((ext_vector_type(8))) __bf16 bf16x8;

__device__ __forceinline__ ushort f2bf(float f) {
  uint u = __float_as_uint(f);
  return (ushort)((u + 0x7fffu + ((u >> 16) & 1u)) >> 16);  // RNE
}
__device__ __forceinline__ uint cvt_pk_bf16(float lo, float hi) {
  uint r;
  asm("v_cvt_pk_bf16_f32 %0, %1, %2" : "=v"(r) : "v"(lo), "v"(hi));
  return r;
}

typedef __attribute__((address_space(1))) void gvoid;
typedef __attribute__((address_space(3))) void lvoid;
__device__ __forceinline__ void load_lds16(const void* g, void* l) {
  __builtin_amdgcn_global_load_lds((gvoid*)g, (lvoid*)l, 16, 0, 0);
}

// ---------------------------------------------------------------------------
// Merged setup kernel: blocks [0,8192) cast x/wqkv/wo to bf16 (float4/thr);
// blocks [8192,8448) fill the RoPE cos/sin table (f64 trig).
// ---------------------------------------------------------------------------
__global__ __launch_bounds__(256) void setup_kernel(
    const float* __restrict__ x, const float* __restrict__ wq,
    const float* __restrict__ wo, ushort* __restrict__ xb,
    ushort* __restrict__ wqb, ushort* __restrict__ wob,
    float2* __restrict__ tab) {
  const int bid = blockIdx.x;
  if (bid < 8192) {
    const int i = bid * 256 + threadIdx.x;
    const float* src;
    ushort* dst;
    int off;
    if (i < 1048576) {
      src = x; dst = xb; off = i;
    } else if (i < 1048576 + 786432) {
      src = wq; dst = wqb; off = i - 1048576;
    } else {
      src = wo; dst = wob; off = i - 1835008;
    }
    const float4 v = reinterpret_cast<const float4*>(src)[off];
    ushort4 o;
    o.x = f2bf(v.x); o.y = f2bf(v.y); o.z = f2bf(v.z); o.w = f2bf(v.w);
    reinterpret_cast<ushort4*>(dst)[off] = o;
  } else {
    const int i = (bid - 8192) * 256 + threadIdx.x;  // 65536 entries
    const int s = i >> 5, p = i & 31;
    const double ang = (double)s * exp2(-(double)p * (kLog2Theta / 32.0));
    tab[i] = make_float2((float)cos(ang), (float)sin(ang));
  }
}

// ---------------------------------------------------------------------------
// QKV projection, 128x128 tile (round-11 mainloop: ONE barrier per K-tile,
// counted waits, both-sides XOR swizzle, 0 bank conflicts measured), fused
// RoPE epilogue + direct V-transpose store. XCD swizzle: xcd = bid&7 owns
// nt in [xcd*3, xcd*3+3); nt fast-varying so each A panel (mt) is reused by
// 3 temporally-adjacent blocks and the 3 B panels stay L2-hot.
// ---------------------------------------------------------------------------
__global__ __launch_bounds__(256) void qkv_mfma_kernel(
    const ushort* __restrict__ xb, const ushort* __restrict__ wqb,
    const float2* __restrict__ tab,
    ushort* __restrict__ q, ushort* __restrict__ k, ushort* __restrict__ vt) {
  __shared__ ushort As0[128 * 64], Bs0[128 * 64];
  __shared__ ushort As1[128 * 64], Bs1[128 * 64];
  const int tid = threadIdx.x;
  const int lane = tid & 63;
  const int wid = tid >> 6;
  const int wm = (wid >> 1) << 6, wn = (wid & 1) << 6;
  const int fr = lane & 15, fq = lane >> 4;

  // XCD swizzle: 768 blocks = 32 mt x 24 nt; xcd owns 3 consecutive nt.
  const int bid = blockIdx.x;
  const int xcd = bid & 7, li = bid >> 3;  // li 0..95
  const int nt = xcd * 3 + (li % 3);
  const int mt = li / 3;
  const int m0 = mt << 7, n0 = nt << 7;

  f32x4 acc[4][4];
#pragma unroll
  for (int i = 0; i < 4; ++i)
#pragma unroll
    for (int j = 0; j < 4; ++j) acc[i][j] = {0.f, 0.f, 0.f, 0.f};

  auto stage = [&](int k0, ushort* Ad, ushort* Bd) {
#pragma unroll
    for (int u = 0; u < 4; ++u) {
      const int c = u * 256 + tid;
      const int r = c >> 3, sl = c & 7;
      const int col = k0 + ((sl ^ (r & 7)) << 3);
      load_lds16(&xb[(size_t)(m0 + r) * kD + col], &Ad[c << 3]);
      load_lds16(&wqb[(size_t)(n0 + r) * kD + col], &Bd[c << 3]);
    }
  };
  auto rdfrag = [&](const ushort* S, int row, int kk) -> bf16x8 {
    const int off = ((kk << 5) + (fq << 3)) ^ ((row & 7) << 3);
    return *reinterpret_cast<const bf16x8*>(&S[(row << 6) + off]);
  };

  stage(0, As0, Bs0);

  auto tile = [&](const ushort* cA, const ushort* cB, ushort* nA, ushort* nB,
                  bool pf, int k0n) {
    asm volatile("s_waitcnt vmcnt(0)" ::: "memory");  // stage(t): old, done
    __builtin_amdgcn_s_barrier();                     // buf[cur] readable
    __builtin_amdgcn_sched_barrier(0);
    bf16x8 af[2][4], bf_[2][4];
#pragma unroll
    for (int kk = 0; kk < 2; ++kk)
#pragma unroll
      for (int f = 0; f < 4; ++f) {
        af[kk][f]  = rdfrag(cA, wm + f * 16 + fr, kk);
        bf_[kk][f] = rdfrag(cB, wn + f * 16 + fr, kk);
      }
    if (pf) stage(k0n, nA, nB);  // prefetch: waited only at NEXT tile top
    asm volatile("s_waitcnt lgkmcnt(0)" ::: "memory");
    __builtin_amdgcn_sched_barrier(0);
    __builtin_amdgcn_s_setprio(1);
#pragma unroll
    for (int kk = 0; kk < 2; ++kk)
#pragma unroll
      for (int i = 0; i < 4; ++i)
#pragma unroll
        for (int j = 0; j < 4; ++j)
          acc[i][j] = __builtin_amdgcn_mfma_f32_16x16x32_bf16(
              af[kk][i], bf_[kk][j], acc[i][j], 0, 0, 0);
    __builtin_amdgcn_s_setprio(0);
  };

  for (int t = 0; t < kNT; t += 2) {
    tile(As0, Bs0, As1, Bs1, true, (t + 1) << 6);
    tile(As1, Bs1, As0, Bs0, t + 2 < kNT, (t + 2) << 6);
  }

  // ---- epilogue: Q/K with RoPE (B,H,S,dk); V stored TRANSPOSED (B,H,dk,S).
  const int tsel = n0 >> 10;  // 0=Q 1=K 2=V (block-uniform; 128 | 1024)
#pragma unroll
  for (int i = 0; i < 4; ++i) {
    const int mbase = m0 + wm + i * 16 + fq * 4;
    const int b = mbase >> 11, sbase = mbase & (kS - 1);
#pragma unroll
    for (int j = 0; j < 4; ++j) {
      const int n = n0 + wn + j * 16 + fr;
      const int h = (n >> 6) & 15, d = n & 63;
      if (tsel == 2) {  // V: 4 consecutive-s values -> one 8B store to Vt
        ushort4 o;
        o.x = f2bf(acc[i][j][0]);
        o.y = f2bf(acc[i][j][1]);
        o.z = f2bf(acc[i][j][2]);
        o.w = f2bf(acc[i][j][3]);
        *reinterpret_cast<ushort4*>(
            &vt[(((size_t)((b << 4) + h) << 6) + d) * kS + sbase]) = o;
      } else {
        ushort* dst = (tsel == 0) ? q : k;
#pragma unroll
        for (int r = 0; r < 4; ++r) {
          const int s = sbase + r;
          float val = acc[i][j][r];
          const float2 cs = tab[(s << 5) + (d >> 1)];
          const float partner = __shfl_xor(val, 1);
          val = (d & 1) ? (partner * cs.y + val * cs.x)
                        : (val * cs.x - partner * cs.y);
          if (tsel == 0) val *= C_SCALE;  // fold softmax scale into Q
          dst[(((size_t)((b << 4) + h) << 11) + s) * kDk + d] = f2bf(val);
        }
      }
    }
  }
}

// ---------------------------------------------------------------------------
// Output projection (128², round-11 mainloop), f32 store. XCD patch swizzle.
// ---------------------------------------------------------------------------
__global__ __launch_bounds__(256) void proj_mfma_kernel(
    const ushort* __restrict__ ab, const ushort* __restrict__ wob,
    float* __restrict__ out) {
  __shared__ ushort As0[128 * 64], Bs0[128 * 64];
  __shared__ ushort As1[128 * 64], Bs1[128 * 64];
  const int tid = threadIdx.x;
  const int lane = tid & 63;
  const int wid = tid >> 6;
  const int wm = (wid >> 1) << 6, wn = (wid & 1) << 6;
  const int fr = lane & 15, fq = lane >> 4;

  const int bid = blockIdx.x;
  const int xcd = bid & 7, li = bid >> 3;            // li 0..31
  const int mt = ((xcd >> 1) << 3) + (li & 7);       // 0..31
  const int ntl = ((xcd & 1) << 2) + (li >> 3);      // 0..7
  const int m0 = mt << 7, n0 = ntl << 7;

  f32x4 acc[4][4];
#pragma unroll
  for (int i = 0; i < 4; ++i)
#pragma unroll
    for (int j = 0; j < 4; ++j) acc[i][j] = {0.f, 0.f, 0.f, 0.f};

  auto stage = [&](int k0, ushort* Ad, ushort* Bd) {
#pragma unroll
    for (int u = 0; u < 4; ++u) {
      const int c = u * 256 + tid;
      const int r = c >> 3, sl = c & 7;
      const int col = k0 + ((sl ^ (r & 7)) << 3);
      load_lds16(&ab[(size_t)(m0 + r) * kD + col], &Ad[c << 3]);
      load_lds16(&wob[(size_t)(n0 + r) * kD + col], &Bd[c << 3]);
    }
  };
  auto rdfrag = [&](const ushort* S, int row, int kk) -> bf16x8 {
    const int off = ((kk << 5) + (fq << 3)) ^ ((row & 7) << 3);
    return *reinterpret_cast<const bf16x8*>(&S[(row << 6) + off]);
  };

  stage(0, As0, Bs0);

  auto tile = [&](const ushort* cA, const ushort* cB, ushort* nA, ushort* nB,
                  bool pf, int k0n) {
    asm volatile("s_waitcnt vmcnt(0)" ::: "memory");
    __builtin_amdgcn_s_barrier();
    __builtin_amdgcn_sched_barrier(0);
    bf16x8 af[2][4], bf_[2][4];
#pragma unroll
    for (int kk = 0; kk < 2; ++kk)
#pragma unroll
      for (int f = 0; f < 4; ++f) {
        af[kk][f]  = rdfrag(cA, wm + f * 16 + fr, kk);
        bf_[kk][f] = rdfrag(cB, wn + f * 16 + fr, kk);
      }
    if (pf) stage(k0n, nA, nB);
    asm volatile("s_waitcnt lgkmcnt(0)" ::: "memory");
    __builtin_amdgcn_sched_barrier(0);
    __builtin_amdgcn_s_setprio(1);
#pragma unroll
    for (int kk = 0; kk < 2; ++kk)
#pragma unroll
      for (int i = 0; i < 4; ++i)
#pragma unroll
        for (int j = 0; j < 4; ++j)
          acc[i][j] = __builtin_amdgcn_mfma_f32_16x16x32_bf16(
              af[kk][i], bf_[kk][j], acc[i][j], 0, 0, 0);
    __builtin_amdgcn_s_setprio(0);
  };

  for (int t = 0; t < kNT; t += 2) {
    tile(As0, Bs0, As1, Bs1, true, (t + 1) << 6);
    tile(As1, Bs1, As0, Bs0, t + 2 < kNT, (t + 2) << 6);
  }

#pragma unroll
  for (int i = 0; i < 4; ++i)
#pragma unroll
    for (int j = 0; j < 4; ++j)
#pragma unroll
      for (int r = 0; r < 4; ++r)
        out[(size_t)(m0 + wm + i * 16 + fq * 4 + r) * kD + n0 + wn + j * 16 + fr] =
            acc[i][j][r];
}

// ---------------------------------------------------------------------------
// Causal flash attention, bf16 MFMA 32x32x16, swapped operands, KVBLK=128,
// static-max softmax. NO LDS STAGING: K and Vt MFMA operands are read
// directly from global (L2-resident per-XCD: 4 heads x 512KB = 2MB < 4MB L2;
// per-tile K+V = 32KB = L1, so intra-block 4-wave redundancy is L1-absorbed).
// Zero barriers in the main loop -> 8 resident waves/CU free-run and hide
// load latency (m169 lesson: staging L2-fit data is pure overhead).
// LDS (16KB) used only for the output transpose epilogue.
// ---------------------------------------------------------------------------
__global__ __launch_bounds__(256) void attn_mfma_kernel(
    const ushort* __restrict__ q, const ushort* __restrict__ k,
    const ushort* __restrict__ vt, ushort* __restrict__ ob) {
  __shared__ ushort smem[8192];        // epilogue transpose only (16KB)
  const int tid = threadIdx.x;
  const int lane = tid & 63;
  const int wq = tid >> 6;             // wave 0..3
  const int l5 = lane >> 5;
  const int ln = lane & 31;            // q column owned by this lane
  const int swz = (ln & 7) << 4;       // epilogue LDS byte swizzle

  // XCD-local decode: xcd = bh>>2 grouping; heavy-qi first within XCD.
  const int bidx = blockIdx.x;
  const int xcd = bidx & 7, li = bidx >> 3;          // li 0..63
  const int bh = (xcd << 2) + (li & 3);
  const int grp = li >> 2;                           // 0..15
  const int qi = (grp < 8) ? (15 - grp) : (grp - 8);
  const int qb = qi << 7;
  const int nt = qi + 1;               // 128-key tiles

  const ushort* qp = q + (size_t)bh * kS * kDk;
  const ushort* kp = k + (size_t)bh * kS * kDk;
  const ushort* vp = vt + (size_t)bh * kDk * kS;  // [d][s]

  // Q fragments (B-operand, persist): dk = kk*16 + l5*8 + j. Q pre-scaled.
  bf16x8 bq[4];
#pragma unroll
  for (int kk = 0; kk < 4; ++kk)
    bq[kk] = *reinterpret_cast<const bf16x8*>(
        &qp[(size_t)(qb + wq * 32 + ln) * kDk + kk * 16 + l5 * 8]);

  f32x16 acc_o[2];
#pragma unroll
  for (int db = 0; db < 2; ++db)
#pragma unroll
    for (int r = 0; r < 16; ++r) acc_o[db][r] = 0.f;
  float l_run = 0.f;

  for (int kt = 0; kt < nt; ++kt) {
    // ---- QK^T: A-operand = K rows, straight from global ----
    f32x16 accs[4];
    __builtin_amdgcn_s_setprio(1);
#pragma unroll
    for (int cb = 0; cb < 4; ++cb) {
#pragma unroll
      for (int r = 0; r < 16; ++r) accs[cb][r] = 0.f;
#pragma unroll
      for (int kk = 0; kk < 4; ++kk) {
        const bf16x8 av = *reinterpret_cast<const bf16x8*>(
            &kp[(size_t)(kt * 128 + cb * 32 + ln) * kDk + kk * 16 + l5 * 8]);
        accs[cb] = __builtin_amdgcn_mfma_f32_32x32x16_bf16(av, bq[kk], accs[cb], 0, 0, 0);
      }
    }
    __builtin_amdgcn_s_setprio(0);

    // ---- causal mask (diagonal tile only) ----
    if (kt == qi) {
      const int lim = (wq << 5) + ln;  // qrow - qb
#pragma unroll
      for (int cb = 0; cb < 4; ++cb)
#pragma unroll
        for (int r = 0; r < 16; ++r) {
          const int key = cb * 32 + (r & 3) + 8 * (r >> 2) + 4 * l5;
          if (key > lim) accs[cb][r] = -INFINITY;
        }
    }

    // ---- static-max softmax: p = exp2(s), accumulate l ----
    uint c8[4][8];
    float lsum = 0.f;
#pragma unroll
    for (int cb = 0; cb < 4; ++cb) {
      float s0 = 0.f, s1 = 0.f, s2 = 0.f, s3 = 0.f;
      float p[16];
#pragma unroll
      for (int r = 0; r < 16; ++r) {
        p[r] = exp2f(accs[cb][r]);
        if ((r & 3) == 0) s0 += p[r];
        else if ((r & 3) == 1) s1 += p[r];
        else if ((r & 3) == 2) s2 += p[r];
        else s3 += p[r];
      }
      lsum += (s0 + s1) + (s2 + s3);
#pragma unroll
      for (int t = 0; t < 8; ++t)
        c8[cb][t] = cvt_pk_bf16(p[2 * t], p[2 * t + 1]);
    }
    l_run += lsum;

    // ---- PV: A-operand = Vt rows, straight from global ----
    __builtin_amdgcn_s_setprio(1);
#pragma unroll
    for (int kb = 0; kb < 8; ++kb) {
      const int cb = kb >> 1, base = (kb & 1) * 4;
      const uint a0 = c8[cb][base + 0], a1 = c8[cb][base + 1];
      const uint b0 = c8[cb][base + 2], b1 = c8[cb][base + 3];
      const uint sa0 = (uint)__shfl_xor((int)a0, 32);
      const uint sa1 = (uint)__shfl_xor((int)a1, 32);
      const uint sb0 = (uint)__shfl_xor((int)b0, 32);
      const uint sb1 = (uint)__shfl_xor((int)b1, 32);
      uint4 dw;
      dw.x = l5 ? sb0 : a0;
      dw.y = l5 ? sb1 : a1;
      dw.z = l5 ? b0 : sa0;
      dw.w = l5 ? b1 : sa1;
      const bf16x8 pa = *reinterpret_cast<const bf16x8*>(&dw);
#pragma unroll
      for (int db = 0; db < 2; ++db) {
        const bf16x8 av = *reinterpret_cast<const bf16x8*>(
            &vp[(size_t)(db * 32 + ln) * kS + kt * 128 + kb * 16 + l5 * 8]);
        acc_o[db] = __builtin_amdgcn_mfma_f32_32x32x16_bf16(av, pa, acc_o[db], 0, 0, 0);
      }
    }
    __builtin_amdgcn_s_setprio(0);
  }

  // ---- combine the two half-wave l partials, normalize, store ----
  const float l_tot = l_run + __shfl_xor(l_run, 32);
  const float linv = 1.f / l_tot;

  __syncthreads();                     // epilogue LDS reuse fence
  char* OsB = reinterpret_cast<char*>(smem);  // Os: [128 q][64 d], swizzled
  const int orow = wq * 32 + ln;
#pragma unroll
  for (int db = 0; db < 2; ++db)
#pragma unroll
    for (int t = 0; t < 8; ++t) {
      const int reg = 2 * t;
      const int d = db * 32 + (reg & 3) + 8 * (reg >> 2) + 4 * l5;
      const uint pk2 = cvt_pk_bf16(acc_o[db][reg] * linv, acc_o[db][reg + 1] * linv);
      *reinterpret_cast<uint*>(OsB + orow * 128 + ((d * 2) ^ swz)) = pk2;
    }
  __syncthreads();
  const int b = bh >> 4, h = bh & 15;
  const int qrw = tid >> 1, half = tid & 1;
  ushort* orow_g = ob + ((size_t)(b * kS + qb + qrw)) * kD + h * kDk + half * 32;
#pragma unroll
  for (int sl = 0; sl < 4; ++sl) {
    const uint4 vdat = *reinterpret_cast<const uint4*>(
        OsB + qrw * 128 + ((half * 64 + sl * 16) ^ ((qrw & 7) << 4)));
    *reinterpret_cast<uint4*>(orow_g + sl * 8) = vdat;
  }
}

// ---------------------------------------------------------------------------
// Workspace (bytes from d_ws base), total ~41 MB:
//   qb 0..8M, kb 8..16M, vtb 16..24M (Vt, (B,H,dk,S) -- written by qkv)
//   xb 24..32M (x bf16; aliased as attnb after QKV GEMM)
//   wqb 32..38M, wob 38..40M, tab 40..40.5M
// ---------------------------------------------------------------------------
extern "C" void kernel_launch(void* const* d_in, const int* in_sizes, int n_in,
                              void* d_out, int out_size, void* d_ws,
                              size_t ws_size, hipStream_t stream) {
  const float* x = (const float*)d_in[0];
  const float* wqkv = (const float*)d_in[1];
  const float* wo = (const float*)d_in[2];
  float* out = (float*)d_out;
  char* w = (char*)d_ws;
  const size_t MB = 1024 * 1024;
  ushort* qb  = (ushort*)(w + 0 * MB);
  ushort* kb  = (ushort*)(w + 8 * MB);
  ushort* vtb = (ushort*)(w + 16 * MB);
  ushort* xb  = (ushort*)(w + 24 * MB);
  ushort* wqb = (ushort*)(w + 32 * MB);
  ushort* wob = (ushort*)(w + 38 * MB);
  float2* tab = (float2*)(w + 40 * MB);
  ushort* attnb = xb;  // alias: x is dead once QKV GEMM completes

  hipLaunchKernelGGL(setup_kernel, dim3(8448), dim3(256), 0, stream,
                     x, wqkv, wo, xb, wqb, wob, tab);
  hipLaunchKernelGGL(qkv_mfma_kernel, dim3(768), dim3(256), 0, stream,
                     xb, wqb, tab, qb, kb, vtb);
  hipLaunchKernelGGL(attn_mfma_kernel, dim3(512), dim3(256), 0, stream,
                     qb, kb, vtb, attnb);
  hipLaunchKernelGGL(proj_mfma_kernel, dim3(256), dim3(256), 0, stream,
                     attnb, wob, out);
}